// Round 9
// baseline (182.140 us; speedup 1.0000x reference)
//
#include <hip/hip_runtime.h>
#include <math.h>

#define N_ 4
#define C_ 64
#define H_ 128
#define W_ 128
#define HW_ (H_ * W_)
#define K2_ 9
#define COUT 64
#define CK 576          // K = 9 taps * 64 channels, order k*64+c
#define TP 16           // pixels per block
#define SST 584         // s_x row stride (elems); 292 dwords ≡ 4 mod 32 -> conflict-safe

typedef __bf16 bf16x8 __attribute__((ext_vector_type(8)));
typedef __bf16 bf16x2 __attribute__((ext_vector_type(2)));
typedef float floatx4 __attribute__((ext_vector_type(4)));
typedef float floatx2 __attribute__((ext_vector_type(2)));

__device__ __forceinline__ float bflo(unsigned u) {
    return __builtin_bit_cast(float, u << 16);
}
__device__ __forceinline__ float bfhi(unsigned u) {
    return __builtin_bit_cast(float, u & 0xffff0000u);
}

// ---- prep: (a) NCHW fp32 -> NHWC bf16 transpose, (b) weight re-layout ----
__global__ __launch_bounds__(256) void prep_kernel(const float* __restrict__ x,
                                                   const float* __restrict__ w,
                                                   const float* __restrict__ w_off,
                                                   __bf16* __restrict__ xT,
                                                   __bf16* __restrict__ w2,
                                                   __bf16* __restrict__ w_off2) {
    __shared__ float s_t[64][33];
    int t = threadIdx.x;
    int bx = blockIdx.x;
    int y = blockIdx.y, n = blockIdx.z;
    if (bx < 4) {
        int x0 = bx * 32;
        int c = t >> 2, seg = (t & 3) * 8;
        const float* src = x + (((size_t)n * C_ + c) * H_ + y) * W_ + x0 + seg;
        floatx4 v0 = *(const floatx4*)src;
        floatx4 v1 = *(const floatx4*)(src + 4);
#pragma unroll
        for (int j = 0; j < 4; ++j) { s_t[c][seg + j] = v0[j]; s_t[c][seg + 4 + j] = v1[j]; }
        __syncthreads();
        int xl = t >> 3, cb = (t & 7) * 8;
        bf16x8 o;
#pragma unroll
        for (int j = 0; j < 8; ++j) o[j] = (__bf16)s_t[cb + j][xl];
        *(bf16x8*)(xT + (((size_t)n * H_ + y) * W_ + x0 + xl) * C_ + cb) = o;
    } else {
        int linear = (n * 128 + y) * 256 + t;
        if (linear < COUT * CK) {
            int o = linear / CK, r = linear - o * CK;
            int k = r >> 6, c = r & 63;
            w2[linear] = (__bf16)w[(o * C_ + c) * K2_ + k];
        }
        if (linear < 32 * CK) {
            int o = linear / CK, r = linear - o * CK;
            int k = r >> 6, c = r & 63;
            w_off2[linear] = (o < 27) ? (__bf16)w_off[(o * C_ + c) * K2_ + k] : (__bf16)0.f;
        }
    }
}

__global__ __launch_bounds__(256) void fused_kernel(const __bf16* __restrict__ xT,
                                                    const __bf16* __restrict__ w2,
                                                    const __bf16* __restrict__ w_off2,
                                                    const float* __restrict__ b_off,
                                                    const float* __restrict__ b,
                                                    float* __restrict__ out) {
    __shared__ __align__(16) __bf16 s_x[TP * SST];   // sampled B^T tile [p][k*64+c]
    __shared__ float s_om[2][32 * TP];               // offset-conv K-half partials [co][p]
    __shared__ floatx4 s_w4[K2_ * TP];               // 4 position-weights (mask folded)
    __shared__ int s_pix[K2_ * TP];                  // clamped base pixel index

    int t = threadIdx.x;
    int pixbase = blockIdx.x * TP;                   // over N*H*W
    int wo0 = pixbase & (W_ - 1);
    int ho  = (pixbase >> 7) & (H_ - 1);
    int n   = pixbase >> 14;
    const __bf16* xn = xT + (size_t)n * HW_ * C_;

    int lane = t & 63;
    int wv   = t >> 6;
    int half = lane >> 5;
    int li   = lane & 31;
    int q    = lane >> 4;
    int col  = lane & 15;

    // integer taps for pixel p=col (for offset-conv B-fragments)
    int  pixk[9];
    bool vk[9];
#pragma unroll
    for (int k = 0; k < 9; ++k) {
        int kh = k / 3, kw = k - kh * 3;
        int y  = ho - 1 + kh;
        int xx = wo0 + col - 1 + kw;
        vk[k] = ((unsigned)y < (unsigned)H_) && ((unsigned)xx < (unsigned)W_);
        int yc = min(max(y, 0), H_ - 1), xc = min(max(xx, 0), W_ - 1);
        pixk[k] = yc * W_ + xc;
    }
    const bf16x8 bz = {(__bf16)0.f, (__bf16)0.f, (__bf16)0.f, (__bf16)0.f,
                       (__bf16)0.f, (__bf16)0.f, (__bf16)0.f, (__bf16)0.f};

    // ---- Phase B: offset conv, all 4 waves: (row-tile r, K-half h) ----
    // B-fragments loaded DIRECTLY from global NHWC (masked), A from w_off2.
    {
        int h = wv & 1;                              // K-half: k in [h*288, h*288+288)
        int r = wv >> 1;                             // row-tile: co 16r..16r+15
        const __bf16* ar = w_off2 + (size_t)(16 * r + col) * CK + h * 288 + q * 8;
        floatx4 acc = {0.f, 0.f, 0.f, 0.f};
#pragma unroll
        for (int i = 0; i < 9; ++i) {
            int ks  = h * 288 + 32 * i;
            int tap = ks >> 6;
            int cb  = ks & 63;                       // 0 or 32
            bf16x8 bb = *(const bf16x8*)(xn + (size_t)pixk[tap] * C_ + cb + q * 8);
            bb = vk[tap] ? bb : bz;
            bf16x8 a = *(const bf16x8*)(ar + 32 * i);
            acc = __builtin_amdgcn_mfma_f32_16x16x32_bf16(a, bb, acc, 0, 0, 0);
        }
#pragma unroll
        for (int rr = 0; rr < 4; ++rr)
            s_om[h][(16 * r + q * 4 + rr) * TP + col] = acc[rr];
    }
    __syncthreads();

    // ---- coords: position-weights + clamped base pixel (144 threads) ----
    if (t < K2_ * TP) {
        int k  = t >> 4;
        int pp = t & 15;
        float dy = s_om[0][(2 * k) * TP + pp]     + s_om[1][(2 * k) * TP + pp]     + b_off[2 * k];
        float dx = s_om[0][(2 * k + 1) * TP + pp] + s_om[1][(2 * k + 1) * TP + pp] + b_off[2 * k + 1];
        float mm = s_om[0][(18 + k) * TP + pp]    + s_om[1][(18 + k) * TP + pp]    + b_off[18 + k];
        float msk = 1.f / (1.f + expf(-mm));
        int kh = k / 3, kw = k - kh * 3;
        float py = (float)(ho - 1 + kh) + dy;
        float px = (float)(wo0 + pp - 1 + kw) + dx;
        float yf = floorf(py), xf = floorf(px);
        float fy = py - yf, fx = px - xf;
        int y0 = (int)yf, x0 = (int)xf;
        float wy0 = ((unsigned)y0 < (unsigned)H_)       ? 1.f - fy : 0.f;
        float wy1 = ((unsigned)(y0 + 1) < (unsigned)H_) ? fy       : 0.f;
        float wx0 = ((unsigned)x0 < (unsigned)W_)       ? 1.f - fx : 0.f;
        float wx1 = ((unsigned)(x0 + 1) < (unsigned)W_) ? fx       : 0.f;
        int y0c = min(max(y0, 0), H_ - 2);
        int x0c = min(max(x0, 0), W_ - 2);
        // shift weights onto clamped positions (OOB-safe addresses, exact zeros)
        float t0 = (y0 == y0c) ? wy0 : ((y0 + 1 == y0c) ? wy1 : 0.f);
        float t1 = (y0 == y0c) ? wy1 : ((y0 == y0c + 1) ? wy0 : 0.f);
        float u0 = (x0 == x0c) ? wx0 : ((x0 + 1 == x0c) ? wx1 : 0.f);
        float u1 = (x0 == x0c) ? wx1 : ((x0 == x0c + 1) ? wx0 : 0.f);
        floatx4 w4 = { t0 * u0 * msk, t0 * u1 * msk, t1 * u0 * msk, t1 * u1 * msk };
        s_w4[t] = w4;
        s_pix[t] = y0c * W_ + x0c;
    }
    __syncthreads();

    // ---- Phase C: bilinear sample; half-wave per (k,p), lane = channel pair ----
    {
        int Pb = wv * 36 + half;
        unsigned buf[3][4];
#pragma unroll
        for (int g = 0; g < 2; ++g) {               // prologue
            int pix = s_pix[Pb + 2 * g];
            const unsigned* bp = (const unsigned*)(xn + (size_t)pix * C_) + li;
            buf[g][0] = bp[0];
            buf[g][1] = bp[32];
            buf[g][2] = bp[W_ * 32];
            buf[g][3] = bp[W_ * 32 + 32];
        }
#pragma unroll
        for (int g = 0; g < 18; ++g) {
            if (g < 16) {                           // issue group g+2
                int pix = s_pix[Pb + 2 * (g + 2)];
                const unsigned* bp = (const unsigned*)(xn + (size_t)pix * C_) + li;
                unsigned* d = buf[(g + 2) % 3];
                d[0] = bp[0];
                d[1] = bp[32];
                d[2] = bp[W_ * 32];
                d[3] = bp[W_ * 32 + 32];
            }
            int P = Pb + 2 * g;
            floatx4 w4 = s_w4[P];
            const unsigned* a = buf[g % 3];
            float lo = w4[0] * bflo(a[0]) + w4[1] * bflo(a[1])
                     + w4[2] * bflo(a[2]) + w4[3] * bflo(a[3]);
            float hi = w4[0] * bfhi(a[0]) + w4[1] * bfhi(a[1])
                     + w4[2] * bfhi(a[2]) + w4[3] * bfhi(a[3]);
            floatx2 fv = {lo, hi};
            bf16x2 bv = __builtin_convertvector(fv, bf16x2);
            int k = P >> 4, p = P & 15;
            *(unsigned*)&s_x[p * SST + k * 64 + 2 * li] = __builtin_bit_cast(unsigned, bv);
        }
    }
    __syncthreads();

    // ---- Phase D: main conv MFMA (4 waves, o-tile = 16*wv), A prefetched depth-1 ----
    {
        const __bf16* ar = w2 + (size_t)(16 * wv + col) * CK + q * 8;
        const __bf16* brow = s_x + col * SST + q * 8;
        floatx4 acc = {0.f, 0.f, 0.f, 0.f};
        bf16x8 a_cur = *(const bf16x8*)ar;
#pragma unroll
        for (int it = 0; it < 18; ++it) {
            bf16x8 a_nxt;
            if (it < 17) a_nxt = *(const bf16x8*)(ar + 32 * (it + 1));
            bf16x8 bb = *(const bf16x8*)(brow + 32 * it);
            acc = __builtin_amdgcn_mfma_f32_16x16x32_bf16(a_cur, bb, acc, 0, 0, 0);
            a_cur = a_nxt;
        }
#pragma unroll
        for (int r = 0; r < 4; ++r) {
            int o = 16 * wv + q * 4 + r;
            float v = acc[r] + b[o];
            out[(((size_t)n * COUT + o) * H_ + ho) * W_ + wo0 + col] = fmaxf(v, 0.f);
        }
    }
}

extern "C" void kernel_launch(void* const* d_in, const int* in_sizes, int n_in,
                              void* d_out, int out_size, void* d_ws, size_t ws_size,
                              hipStream_t stream) {
    const float* x     = (const float*)d_in[0];
    const float* w_off = (const float*)d_in[1];
    const float* b_off = (const float*)d_in[2];
    const float* w     = (const float*)d_in[3];
    const float* b     = (const float*)d_in[4];
    float* out = (float*)d_out;

    // workspace: xT (NHWC bf16, 8.39 MB) | w2 (64x576 bf16) | w_off2 (32x576 bf16)
    __bf16* xT     = (__bf16*)d_ws;
    __bf16* w2     = xT + (size_t)N_ * HW_ * C_;
    __bf16* w_off2 = w2 + (size_t)COUT * CK;

    prep_kernel<<<dim3(5, 128, 4), 256, 0, stream>>>(x, w, w_off, xT, w2, w_off2);

    int nblocks = N_ * H_ * W_ / TP;   // 4096
    fused_kernel<<<nblocks, 256, 0, stream>>>(xT, w2, w_off2, b_off, b, out);
}

// Round 10
// 149.615 us; speedup vs baseline: 1.2174x; 1.2174x over previous
//
#include <hip/hip_runtime.h>
#include <math.h>

#define N_ 4
#define C_ 64
#define H_ 128
#define W_ 128
#define HW_ (H_ * W_)
#define K2_ 9
#define COUT 64
#define CK 576          // K = 9 taps * 64 channels, order k*64+c
#define TP 16           // pixels per block
#define SST 584         // s_x row stride (elems)

typedef __bf16 bf16x8 __attribute__((ext_vector_type(8)));
typedef __bf16 bf16x2 __attribute__((ext_vector_type(2)));
typedef float floatx4 __attribute__((ext_vector_type(4)));
typedef float floatx2 __attribute__((ext_vector_type(2)));

__device__ __forceinline__ float bflo(unsigned u) {
    return __builtin_bit_cast(float, u << 16);
}
__device__ __forceinline__ float bfhi(unsigned u) {
    return __builtin_bit_cast(float, u & 0xffff0000u);
}

// ---- prep: (a) NCHW fp32 -> NHWC bf16 transpose, (b) weight re-layout ----
__global__ __launch_bounds__(256) void prep_kernel(const float* __restrict__ x,
                                                   const float* __restrict__ w,
                                                   const float* __restrict__ w_off,
                                                   __bf16* __restrict__ xT,
                                                   __bf16* __restrict__ w2,
                                                   __bf16* __restrict__ w_off2) {
    __shared__ float s_t[64][33];
    int t = threadIdx.x;
    int bx = blockIdx.x;
    int y = blockIdx.y, n = blockIdx.z;
    if (bx < 4) {
        int x0 = bx * 32;
        int c = t >> 2, seg = (t & 3) * 8;
        const float* src = x + (((size_t)n * C_ + c) * H_ + y) * W_ + x0 + seg;
        floatx4 v0 = *(const floatx4*)src;
        floatx4 v1 = *(const floatx4*)(src + 4);
#pragma unroll
        for (int j = 0; j < 4; ++j) { s_t[c][seg + j] = v0[j]; s_t[c][seg + 4 + j] = v1[j]; }
        __syncthreads();
        int xl = t >> 3, cb = (t & 7) * 8;
        bf16x8 o;
#pragma unroll
        for (int j = 0; j < 8; ++j) o[j] = (__bf16)s_t[cb + j][xl];
        *(bf16x8*)(xT + (((size_t)n * H_ + y) * W_ + x0 + xl) * C_ + cb) = o;
    } else {
        int linear = (n * 128 + y) * 256 + t;
        if (linear < COUT * CK) {
            int o = linear / CK, r = linear - o * CK;
            int k = r >> 6, c = r & 63;
            w2[linear] = (__bf16)w[(o * C_ + c) * K2_ + k];
        }
        if (linear < 32 * CK) {
            int o = linear / CK, r = linear - o * CK;
            int k = r >> 6, c = r & 63;
            w_off2[linear] = (o < 27) ? (__bf16)w_off[(o * C_ + c) * K2_ + k] : (__bf16)0.f;
        }
    }
}

__global__ __launch_bounds__(256) void fused_kernel(const __bf16* __restrict__ xT,
                                                    const __bf16* __restrict__ w2,
                                                    const __bf16* __restrict__ w_off2,
                                                    const float* __restrict__ b_off,
                                                    const float* __restrict__ b,
                                                    float* __restrict__ out) {
    __shared__ __align__(16) __bf16 s_x[TP * SST];   // sampled B^T tile [p][k*64+c]
    __shared__ float s_om[2][32 * TP];               // offset-conv K-half partials [co][p]
    __shared__ floatx4 s_w4[K2_ * TP];               // 4 position-weights (mask folded)
    __shared__ int s_pix[K2_ * TP];                  // clamped base pixel index

    int t = threadIdx.x;
    int pixbase = blockIdx.x * TP;                   // over N*H*W
    int wo0 = pixbase & (W_ - 1);
    int ho  = (pixbase >> 7) & (H_ - 1);
    int n   = pixbase >> 14;
    const __bf16* xn = xT + (size_t)n * HW_ * C_;

    int lane = t & 63;
    int wv   = t >> 6;
    int half = lane >> 5;
    int li   = lane & 31;
    int q    = lane >> 4;
    int col  = lane & 15;

    // integer taps for pixel p=col (constant-indexed only -> stays in VGPRs)
    int  pixk[9];
    bool vk[9];
#pragma unroll
    for (int k = 0; k < 9; ++k) {
        int kh = k / 3, kw = k - kh * 3;
        int y  = ho - 1 + kh;
        int xx = wo0 + col - 1 + kw;
        vk[k] = ((unsigned)y < (unsigned)H_) && ((unsigned)xx < (unsigned)W_);
        int yc = min(max(y, 0), H_ - 1), xc = min(max(xx, 0), W_ - 1);
        pixk[k] = yc * W_ + xc;
    }
    const bf16x8 bz = {(__bf16)0.f, (__bf16)0.f, (__bf16)0.f, (__bf16)0.f,
                       (__bf16)0.f, (__bf16)0.f, (__bf16)0.f, (__bf16)0.f};

    // ---- Phase B: offset conv, 4 waves = (row-tile r, K-half h); literal tap indices ----
    {
        int r = wv >> 1;
        int h = wv & 1;
        const __bf16* ar = w_off2 + (size_t)(16 * r + col) * CK + h * 288 + q * 8;
        floatx4 acc = {0.f, 0.f, 0.f, 0.f};
#define BSTEP(i, tap, cb)                                                              \
        {                                                                              \
            bf16x8 bb = *(const bf16x8*)(xn + (size_t)pixk[tap] * C_ + (cb) + q * 8);  \
            bb = vk[tap] ? bb : bz;                                                    \
            bf16x8 a = *(const bf16x8*)(ar + 32 * (i));                                \
            acc = __builtin_amdgcn_mfma_f32_16x16x32_bf16(a, bb, acc, 0, 0, 0);        \
        }
        if (h == 0) {
            BSTEP(0, 0, 0)  BSTEP(1, 0, 32) BSTEP(2, 1, 0)  BSTEP(3, 1, 32)
            BSTEP(4, 2, 0)  BSTEP(5, 2, 32) BSTEP(6, 3, 0)  BSTEP(7, 3, 32)
            BSTEP(8, 4, 0)
        } else {
            BSTEP(0, 4, 32) BSTEP(1, 5, 0)  BSTEP(2, 5, 32) BSTEP(3, 6, 0)
            BSTEP(4, 6, 32) BSTEP(5, 7, 0)  BSTEP(6, 7, 32) BSTEP(7, 8, 0)
            BSTEP(8, 8, 32)
        }
#undef BSTEP
#pragma unroll
        for (int rr = 0; rr < 4; ++rr)
            s_om[h][(16 * r + q * 4 + rr) * TP + col] = acc[rr];
    }
    __syncthreads();

    // ---- coords: position-weights + clamped base pixel (144 threads) ----
    if (t < K2_ * TP) {
        int k  = t >> 4;
        int pp = t & 15;
        float dy = s_om[0][(2 * k) * TP + pp]     + s_om[1][(2 * k) * TP + pp]     + b_off[2 * k];
        float dx = s_om[0][(2 * k + 1) * TP + pp] + s_om[1][(2 * k + 1) * TP + pp] + b_off[2 * k + 1];
        float mm = s_om[0][(18 + k) * TP + pp]    + s_om[1][(18 + k) * TP + pp]    + b_off[18 + k];
        float msk = 1.f / (1.f + expf(-mm));
        int kh = k / 3, kw = k - kh * 3;
        float py = (float)(ho - 1 + kh) + dy;
        float px = (float)(wo0 + pp - 1 + kw) + dx;
        float yf = floorf(py), xf = floorf(px);
        float fy = py - yf, fx = px - xf;
        int y0 = (int)yf, x0 = (int)xf;
        float wy0 = ((unsigned)y0 < (unsigned)H_)       ? 1.f - fy : 0.f;
        float wy1 = ((unsigned)(y0 + 1) < (unsigned)H_) ? fy       : 0.f;
        float wx0 = ((unsigned)x0 < (unsigned)W_)       ? 1.f - fx : 0.f;
        float wx1 = ((unsigned)(x0 + 1) < (unsigned)W_) ? fx       : 0.f;
        int y0c = min(max(y0, 0), H_ - 2);
        int x0c = min(max(x0, 0), W_ - 2);
        // shift weights onto clamped positions (OOB-safe addresses, exact zeros)
        float t0 = (y0 == y0c) ? wy0 : ((y0 + 1 == y0c) ? wy1 : 0.f);
        float t1 = (y0 == y0c) ? wy1 : ((y0 == y0c + 1) ? wy0 : 0.f);
        float u0 = (x0 == x0c) ? wx0 : ((x0 + 1 == x0c) ? wx1 : 0.f);
        float u1 = (x0 == x0c) ? wx1 : ((x0 == x0c + 1) ? wx0 : 0.f);
        floatx4 w4 = { t0 * u0 * msk, t0 * u1 * msk, t1 * u0 * msk, t1 * u1 * msk };
        s_w4[t] = w4;
        s_pix[t] = y0c * W_ + x0c;
    }
    __syncthreads();

    // ---- Phase C: bilinear sample; half-wave per (k,p), lane = channel pair ----
    {
        int Pb = wv * 36 + half;
        unsigned buf[3][4];
#pragma unroll
        for (int g = 0; g < 2; ++g) {               // prologue
            int pix = s_pix[Pb + 2 * g];
            const unsigned* bp = (const unsigned*)(xn + (size_t)pix * C_) + li;
            buf[g][0] = bp[0];
            buf[g][1] = bp[32];
            buf[g][2] = bp[W_ * 32];
            buf[g][3] = bp[W_ * 32 + 32];
        }
#pragma unroll
        for (int g = 0; g < 18; ++g) {
            if (g < 16) {                           // issue group g+2
                int pix = s_pix[Pb + 2 * (g + 2)];
                const unsigned* bp = (const unsigned*)(xn + (size_t)pix * C_) + li;
                unsigned* d = buf[(g + 2) % 3];
                d[0] = bp[0];
                d[1] = bp[32];
                d[2] = bp[W_ * 32];
                d[3] = bp[W_ * 32 + 32];
            }
            int P = Pb + 2 * g;
            floatx4 w4 = s_w4[P];
            const unsigned* a = buf[g % 3];
            float lo = w4[0] * bflo(a[0]) + w4[1] * bflo(a[1])
                     + w4[2] * bflo(a[2]) + w4[3] * bflo(a[3]);
            float hi = w4[0] * bfhi(a[0]) + w4[1] * bfhi(a[1])
                     + w4[2] * bfhi(a[2]) + w4[3] * bfhi(a[3]);
            floatx2 fv = {lo, hi};
            bf16x2 bv = __builtin_convertvector(fv, bf16x2);
            int k = P >> 4, p = P & 15;
            *(unsigned*)&s_x[p * SST + k * 64 + 2 * li] = __builtin_bit_cast(unsigned, bv);
        }
    }
    __syncthreads();

    // ---- Phase D: main conv MFMA (4 waves, o-tile = 16*wv), A prefetched depth-1 ----
    {
        const __bf16* ar = w2 + (size_t)(16 * wv + col) * CK + q * 8;
        const __bf16* brow = s_x + col * SST + q * 8;
        floatx4 acc = {0.f, 0.f, 0.f, 0.f};
        bf16x8 a_cur = *(const bf16x8*)ar;
#pragma unroll
        for (int it = 0; it < 18; ++it) {
            bf16x8 a_nxt;
            if (it < 17) a_nxt = *(const bf16x8*)(ar + 32 * (it + 1));
            bf16x8 bb = *(const bf16x8*)(brow + 32 * it);
            acc = __builtin_amdgcn_mfma_f32_16x16x32_bf16(a_cur, bb, acc, 0, 0, 0);
            a_cur = a_nxt;
        }
#pragma unroll
        for (int r = 0; r < 4; ++r) {
            int o = 16 * wv + q * 4 + r;
            float v = acc[r] + b[o];
            out[(((size_t)n * COUT + o) * H_ + ho) * W_ + wo0 + col] = fmaxf(v, 0.f);
        }
    }
}

extern "C" void kernel_launch(void* const* d_in, const int* in_sizes, int n_in,
                              void* d_out, int out_size, void* d_ws, size_t ws_size,
                              hipStream_t stream) {
    const float* x     = (const float*)d_in[0];
    const float* w_off = (const float*)d_in[1];
    const float* b_off = (const float*)d_in[2];
    const float* w     = (const float*)d_in[3];
    const float* b     = (const float*)d_in[4];
    float* out = (float*)d_out;

    // workspace: xT (NHWC bf16, 8.39 MB) | w2 (64x576 bf16) | w_off2 (32x576 bf16)
    __bf16* xT     = (__bf16*)d_ws;
    __bf16* w2     = xT + (size_t)N_ * HW_ * C_;
    __bf16* w_off2 = w2 + (size_t)COUT * CK;

    prep_kernel<<<dim3(5, 128, 4), 256, 0, stream>>>(x, w, w_off, xT, w2, w_off2);

    int nblocks = N_ * H_ * W_ / TP;   // 4096
    fused_kernel<<<nblocks, 256, 0, stream>>>(xT, w2, w_off2, b_off, b, out);
}

// Round 12
// 123.886 us; speedup vs baseline: 1.4702x; 1.2077x over previous
//
#include <hip/hip_runtime.h>
#include <math.h>

#define N_ 4
#define C_ 64
#define H_ 128
#define W_ 128
#define HW_ (H_ * W_)
#define K2_ 9
#define COUT 64
#define CK 576          // K = 9 taps * 64 channels, order k*64+c
#define TP 16           // pixels per tile
#define NT 2            // tiles per block
#define SST 584         // s_x row stride (elems)

typedef __bf16 bf16x8 __attribute__((ext_vector_type(8)));
typedef __bf16 bf16x2 __attribute__((ext_vector_type(2)));
typedef float floatx4 __attribute__((ext_vector_type(4)));
typedef float floatx2 __attribute__((ext_vector_type(2)));

__device__ __forceinline__ float bflo(unsigned u) {
    return __builtin_bit_cast(float, u << 16);
}
__device__ __forceinline__ float bfhi(unsigned u) {
    return __builtin_bit_cast(float, u & 0xffff0000u);
}

// ---- prep: (a) NCHW fp32 -> NHWC bf16 transpose, (b) weight re-layout ----
__global__ __launch_bounds__(256) void prep_kernel(const float* __restrict__ x,
                                                   const float* __restrict__ w,
                                                   const float* __restrict__ w_off,
                                                   __bf16* __restrict__ xT,
                                                   __bf16* __restrict__ w2,
                                                   __bf16* __restrict__ w_off2) {
    __shared__ float s_t[64][33];
    int t = threadIdx.x;
    int bx = blockIdx.x;
    int y = blockIdx.y, n = blockIdx.z;
    if (bx < 4) {
        int x0 = bx * 32;
        int c = t >> 2, seg = (t & 3) * 8;
        const float* src = x + (((size_t)n * C_ + c) * H_ + y) * W_ + x0 + seg;
        floatx4 v0 = *(const floatx4*)src;
        floatx4 v1 = *(const floatx4*)(src + 4);
#pragma unroll
        for (int j = 0; j < 4; ++j) { s_t[c][seg + j] = v0[j]; s_t[c][seg + 4 + j] = v1[j]; }
        __syncthreads();
        int xl = t >> 3, cb = (t & 7) * 8;
        bf16x8 o;
#pragma unroll
        for (int j = 0; j < 8; ++j) o[j] = (__bf16)s_t[cb + j][xl];
        *(bf16x8*)(xT + (((size_t)n * H_ + y) * W_ + x0 + xl) * C_ + cb) = o;
    } else {
        int linear = (n * 128 + y) * 256 + t;
        if (linear < COUT * CK) {
            int o = linear / CK, r = linear - o * CK;
            int k = r >> 6, c = r & 63;
            w2[linear] = (__bf16)w[(o * C_ + c) * K2_ + k];
        }
        if (linear < 32 * CK) {
            int o = linear / CK, r = linear - o * CK;
            int k = r >> 6, c = r & 63;
            w_off2[linear] = (o < 27) ? (__bf16)w_off[(o * C_ + c) * K2_ + k] : (__bf16)0.f;
        }
    }
}

__global__ __launch_bounds__(256) void fused_kernel(const __bf16* __restrict__ xT,
                                                    const __bf16* __restrict__ w2,
                                                    const __bf16* __restrict__ w_off2,
                                                    const float* __restrict__ b_off,
                                                    const float* __restrict__ b,
                                                    float* __restrict__ out) {
    __shared__ __align__(16) __bf16 s_x[NT][TP * SST];  // sampled B^T tiles [p][k*64+c]
    __shared__ float s_om[NT][2][32 * TP];              // offset-conv K-half partials
    __shared__ floatx4 s_w4[NT][K2_ * TP];              // position weights (mask folded)
    __shared__ int s_pix[NT][K2_ * TP];                 // clamped base pixel index

    int t = threadIdx.x;
    int pixbase = blockIdx.x * (TP * NT);               // over N*H*W, 32 px/block
    int wo0 = pixbase & (W_ - 1);                       // 0,32,64,96 (never crosses row)
    int ho  = (pixbase >> 7) & (H_ - 1);
    int n   = pixbase >> 14;
    const __bf16* xn = xT + (size_t)n * HW_ * C_;

    int lane = t & 63;
    int wv   = t >> 6;
    int half = lane >> 5;
    int li   = lane & 31;
    int q    = lane >> 4;
    int col  = lane & 15;

    // ---- Phase A: integer-tap im2col for both tiles (36 loads in flight) ----
    {
        unsigned ua[36];
#pragma unroll
        for (int j = 0; j < 36; ++j) {
            int tl = j / 18, jj = j - 18 * tl;
            int P = wv * 36 + 2 * jj + half;            // P = k*16 + p
            int k = P >> 4, p = P & 15;
            int kh = k / 3, kw = k - kh * 3;
            int y  = ho - 1 + kh;
            int xx = wo0 + 16 * tl + p - 1 + kw;
            int yc  = min(max(y, 0), H_ - 1);
            int xc2 = min(max(xx, 0), W_ - 1);
            unsigned pix = (unsigned)(yc * W_ + xc2);
            ua[j] = *(const unsigned*)(xn + (size_t)pix * C_ + 2 * li);
        }
#pragma unroll
        for (int j = 0; j < 36; ++j) {
            int tl = j / 18, jj = j - 18 * tl;
            int P = wv * 36 + 2 * jj + half;
            int k = P >> 4, p = P & 15;
            int kh = k / 3, kw = k - kh * 3;
            int y  = ho - 1 + kh;
            int xx = wo0 + 16 * tl + p - 1 + kw;
            bool valid = ((unsigned)y < (unsigned)H_) && ((unsigned)xx < (unsigned)W_);
            unsigned v = valid ? ua[j] : 0u;
            *(unsigned*)&s_x[tl][p * SST + k * 64 + 2 * li] = v;
        }
    }
    __syncthreads();

    // ---- Phase B: offset conv, 4 waves = (row-tile r, K-half h); B from LDS; A shared ----
    {
        int r = wv >> 1;
        int h = wv & 1;
        const __bf16* ar = w_off2 + (size_t)(16 * r + col) * CK + h * 288 + q * 8;
        const __bf16* b0 = s_x[0] + col * SST + h * 288 + q * 8;
        const __bf16* b1 = s_x[1] + col * SST + h * 288 + q * 8;
        floatx4 acc0 = {0.f, 0.f, 0.f, 0.f}, acc1 = {0.f, 0.f, 0.f, 0.f};
#pragma unroll
        for (int it = 0; it < 9; ++it) {
            bf16x8 a   = *(const bf16x8*)(ar + 32 * it);
            bf16x8 bb0 = *(const bf16x8*)(b0 + 32 * it);
            bf16x8 bb1 = *(const bf16x8*)(b1 + 32 * it);
            acc0 = __builtin_amdgcn_mfma_f32_16x16x32_bf16(a, bb0, acc0, 0, 0, 0);
            acc1 = __builtin_amdgcn_mfma_f32_16x16x32_bf16(a, bb1, acc1, 0, 0, 0);
        }
#pragma unroll
        for (int rr = 0; rr < 4; ++rr) {
            s_om[0][h][(16 * r + q * 4 + rr) * TP + col] = acc0[rr];
            s_om[1][h][(16 * r + q * 4 + rr) * TP + col] = acc1[rr];
        }
    }
    __syncthreads();

    // ---- coords: position-weights + clamped base pixel (288 items, 2 passes) ----
#pragma unroll
    for (int it2 = 0; it2 < 2; ++it2) {
        int i = it2 * 256 + t;
        if (i < NT * K2_ * TP) {
            int tl = (i >= 144);
            int P  = i - 144 * tl;
            int k  = P >> 4;
            int pp = P & 15;
            float dy = s_om[tl][0][(2 * k) * TP + pp]     + s_om[tl][1][(2 * k) * TP + pp]     + b_off[2 * k];
            float dx = s_om[tl][0][(2 * k + 1) * TP + pp] + s_om[tl][1][(2 * k + 1) * TP + pp] + b_off[2 * k + 1];
            float mm = s_om[tl][0][(18 + k) * TP + pp]    + s_om[tl][1][(18 + k) * TP + pp]    + b_off[18 + k];
            float msk = 1.f / (1.f + expf(-mm));
            int kh = k / 3, kw = k - kh * 3;
            float py = (float)(ho - 1 + kh) + dy;
            float px = (float)(wo0 + 16 * tl + pp - 1 + kw) + dx;
            float yf = floorf(py), xf = floorf(px);
            float fy = py - yf, fx = px - xf;
            int y0 = (int)yf, x0 = (int)xf;
            float wy0 = ((unsigned)y0 < (unsigned)H_)       ? 1.f - fy : 0.f;
            float wy1 = ((unsigned)(y0 + 1) < (unsigned)H_) ? fy       : 0.f;
            float wx0 = ((unsigned)x0 < (unsigned)W_)       ? 1.f - fx : 0.f;
            float wx1 = ((unsigned)(x0 + 1) < (unsigned)W_) ? fx       : 0.f;
            int y0c = min(max(y0, 0), H_ - 2);
            int x0c = min(max(x0, 0), W_ - 2);
            // shift weights onto clamped positions (OOB-safe addresses, exact zeros)
            float t0 = (y0 == y0c) ? wy0 : ((y0 + 1 == y0c) ? wy1 : 0.f);
            float t1 = (y0 == y0c) ? wy1 : ((y0 == y0c + 1) ? wy0 : 0.f);
            float u0 = (x0 == x0c) ? wx0 : ((x0 + 1 == x0c) ? wx1 : 0.f);
            float u1 = (x0 == x0c) ? wx1 : ((x0 == x0c + 1) ? wx0 : 0.f);
            floatx4 w4 = { t0 * u0 * msk, t0 * u1 * msk, t1 * u0 * msk, t1 * u1 * msk };
            s_w4[tl][P] = w4;
            s_pix[tl][P] = y0c * W_ + x0c;
        }
    }
    __syncthreads();

    // ---- Phase C: bilinear sample; half-wave per (k,p); 36 groups pipelined depth-2 ----
    {
        int Pb = wv * 36 + half;
        unsigned buf[3][4];
#pragma unroll
        for (int g = 0; g < 2; ++g) {               // prologue (both in tile 0)
            int pix = s_pix[0][Pb + 2 * g];
            const unsigned* bp = (const unsigned*)(xn + (size_t)pix * C_) + li;
            buf[g][0] = bp[0];
            buf[g][1] = bp[32];
            buf[g][2] = bp[W_ * 32];
            buf[g][3] = bp[W_ * 32 + 32];
        }
#pragma unroll
        for (int g = 0; g < 36; ++g) {
            if (g < 34) {                           // issue group g+2
                int gn = g + 2;
                int tln = (gn >= 18);
                int pix = s_pix[tln][Pb + 2 * (gn - 18 * tln)];
                const unsigned* bp = (const unsigned*)(xn + (size_t)pix * C_) + li;
                unsigned* d = buf[gn % 3];
                d[0] = bp[0];
                d[1] = bp[32];
                d[2] = bp[W_ * 32];
                d[3] = bp[W_ * 32 + 32];
            }
            int tl = (g >= 18);
            int P = Pb + 2 * (g - 18 * tl);
            floatx4 w4 = s_w4[tl][P];
            const unsigned* a = buf[g % 3];
            float lo = w4[0] * bflo(a[0]) + w4[1] * bflo(a[1])
                     + w4[2] * bflo(a[2]) + w4[3] * bflo(a[3]);
            float hi = w4[0] * bfhi(a[0]) + w4[1] * bfhi(a[1])
                     + w4[2] * bfhi(a[2]) + w4[3] * bfhi(a[3]);
            floatx2 fv = {lo, hi};
            bf16x2 bv = __builtin_convertvector(fv, bf16x2);
            int k = P >> 4, p = P & 15;
            *(unsigned*)&s_x[tl][p * SST + k * 64 + 2 * li] = __builtin_bit_cast(unsigned, bv);
        }
    }
    __syncthreads();

    // ---- Phase D: main conv MFMA, A-fragments shared across both tiles ----
    {
        const __bf16* ar = w2 + (size_t)(16 * wv + col) * CK + q * 8;
        const __bf16* b0 = s_x[0] + col * SST + q * 8;
        const __bf16* b1 = s_x[1] + col * SST + q * 8;
        floatx4 acc0 = {0.f, 0.f, 0.f, 0.f}, acc1 = {0.f, 0.f, 0.f, 0.f};
        bf16x8 a_cur = *(const bf16x8*)ar;
#pragma unroll
        for (int it = 0; it < 18; ++it) {
            bf16x8 a_nxt;
            if (it < 17) a_nxt = *(const bf16x8*)(ar + 32 * (it + 1));
            bf16x8 bb0 = *(const bf16x8*)(b0 + 32 * it);
            bf16x8 bb1 = *(const bf16x8*)(b1 + 32 * it);
            acc0 = __builtin_amdgcn_mfma_f32_16x16x32_bf16(a_cur, bb0, acc0, 0, 0, 0);
            acc1 = __builtin_amdgcn_mfma_f32_16x16x32_bf16(a_cur, bb1, acc1, 0, 0, 0);
            a_cur = a_nxt;
        }
#pragma unroll
        for (int r = 0; r < 4; ++r) {
            int o = 16 * wv + q * 4 + r;
            float bias = b[o];
            float* ob = out + (((size_t)n * COUT + o) * H_ + ho) * W_ + wo0;
            ob[col]      = fmaxf(acc0[r] + bias, 0.f);
            ob[16 + col] = fmaxf(acc1[r] + bias, 0.f);
        }
    }
}

extern "C" void kernel_launch(void* const* d_in, const int* in_sizes, int n_in,
                              void* d_out, int out_size, void* d_ws, size_t ws_size,
                              hipStream_t stream) {
    const float* x     = (const float*)d_in[0];
    const float* w_off = (const float*)d_in[1];
    const float* b_off = (const float*)d_in[2];
    const float* w     = (const float*)d_in[3];
    const float* b     = (const float*)d_in[4];
    float* out = (float*)d_out;

    // workspace: xT (NHWC bf16, 8.39 MB) | w2 (64x576 bf16) | w_off2 (32x576 bf16)
    __bf16* xT     = (__bf16*)d_ws;
    __bf16* w2     = xT + (size_t)N_ * HW_ * C_;
    __bf16* w_off2 = w2 + (size_t)COUT * CK;

    prep_kernel<<<dim3(5, 128, 4), 256, 0, stream>>>(x, w, w_off, xT, w2, w_off2);

    int nblocks = N_ * H_ * W_ / (TP * NT);   // 2048
    fused_kernel<<<nblocks, 256, 0, stream>>>(xT, w2, w_off2, b_off, b, out);
}

// Round 13
// 119.398 us; speedup vs baseline: 1.5255x; 1.0376x over previous
//
#include <hip/hip_runtime.h>
#include <math.h>

#define N_ 4
#define C_ 64
#define H_ 128
#define W_ 128
#define HW_ (H_ * W_)
#define K2_ 9
#define COUT 64
#define CK 576          // K = 9 taps * 64 channels, order k*64+c
#define TP 16           // pixels per tile
#define NT 2            // tiles per block
#define SST 584         // s_x row stride (elems)
#define GUARD 128       // guard elems (256 B) before/after xT for unclamped-x loads

typedef __bf16 bf16x8 __attribute__((ext_vector_type(8)));
typedef __bf16 bf16x2 __attribute__((ext_vector_type(2)));
typedef float floatx4 __attribute__((ext_vector_type(4)));
typedef float floatx2 __attribute__((ext_vector_type(2)));
typedef unsigned uint2v __attribute__((ext_vector_type(2)));

__device__ __forceinline__ float bflo(unsigned u) {
    return __builtin_bit_cast(float, u << 16);
}
__device__ __forceinline__ float bfhi(unsigned u) {
    return __builtin_bit_cast(float, u & 0xffff0000u);
}

// ---- prep: (a) NCHW fp32 -> NHWC bf16 transpose, (b) weight re-layout ----
__global__ __launch_bounds__(256) void prep_kernel(const float* __restrict__ x,
                                                   const float* __restrict__ w,
                                                   const float* __restrict__ w_off,
                                                   __bf16* __restrict__ xT,
                                                   __bf16* __restrict__ w2,
                                                   __bf16* __restrict__ w_off2) {
    __shared__ float s_t[64][33];
    int t = threadIdx.x;
    int bx = blockIdx.x;
    int y = blockIdx.y, n = blockIdx.z;
    if (bx < 4) {
        int x0 = bx * 32;
        int c = t >> 2, seg = (t & 3) * 8;
        const float* src = x + (((size_t)n * C_ + c) * H_ + y) * W_ + x0 + seg;
        floatx4 v0 = *(const floatx4*)src;
        floatx4 v1 = *(const floatx4*)(src + 4);
#pragma unroll
        for (int j = 0; j < 4; ++j) { s_t[c][seg + j] = v0[j]; s_t[c][seg + 4 + j] = v1[j]; }
        __syncthreads();
        int xl = t >> 3, cb = (t & 7) * 8;
        bf16x8 o;
#pragma unroll
        for (int j = 0; j < 8; ++j) o[j] = (__bf16)s_t[cb + j][xl];
        *(bf16x8*)(xT + (((size_t)n * H_ + y) * W_ + x0 + xl) * C_ + cb) = o;
    } else {
        int linear = (n * 128 + y) * 256 + t;
        if (linear < COUT * CK) {
            int o = linear / CK, r = linear - o * CK;
            int k = r >> 6, c = r & 63;
            w2[linear] = (__bf16)w[(o * C_ + c) * K2_ + k];
        }
        if (linear < 32 * CK) {
            int o = linear / CK, r = linear - o * CK;
            int k = r >> 6, c = r & 63;
            w_off2[linear] = (o < 27) ? (__bf16)w_off[(o * C_ + c) * K2_ + k] : (__bf16)0.f;
        }
    }
}

__global__ __launch_bounds__(256) void fused_kernel(const __bf16* __restrict__ xT,
                                                    const __bf16* __restrict__ w2,
                                                    const __bf16* __restrict__ w_off2,
                                                    const float* __restrict__ b_off,
                                                    const float* __restrict__ b,
                                                    float* __restrict__ out) {
    __shared__ __align__(16) __bf16 s_x[NT][TP * SST];  // sampled B^T tiles [p][k*64+c]
    __shared__ float s_om[NT][2][32 * TP];              // offset-conv K-half partials
    __shared__ floatx4 s_w4[NT][K2_ * TP];              // position weights (mask folded)
    __shared__ int s_pix[NT][K2_ * TP];                 // clamped base pixel index

    int t = threadIdx.x;
    int pixbase = blockIdx.x * (TP * NT);               // over N*H*W, 32 px/block
    int wo0 = pixbase & (W_ - 1);                       // 0,32,64,96 (never crosses row)
    int ho  = (pixbase >> 7) & (H_ - 1);
    int n   = pixbase >> 14;
    const __bf16* xn = xT + (size_t)n * HW_ * C_;

    int lane = t & 63;
    int wv   = t >> 6;
    int half = lane >> 5;
    int li   = lane & 31;
    int q    = lane >> 4;
    int col  = lane & 15;

    // ---- Phase A: im2col, pixel-PAIR dwordx2 loads (18/wave, guarded unclamped-x) ----
    {
        uint2v ua[18];
        int tl = wv >> 1;                               // wave-uniform tile
        int rb = (wv & 1) * 36 + half;                  // pair index base within tile
#pragma unroll
        for (int j = 0; j < 18; ++j) {
            int r  = rb + 2 * j;                        // 0..71: k = r>>3, pj = r&7
            int k  = r >> 3;
            int p0 = (r & 7) * 2;
            int kh = k / 3, kw = k - kh * 3;
            int y  = ho - 1 + kh;
            int yc = min(max(y, 0), H_ - 1);
            int xx = wo0 + 16 * tl + p0 - 1 + kw;       // unclamped: -1..127 (pair: xx, xx+1)
            int pix = yc * W_ + xx;                     // guard makes -1/OOB reads safe
            ua[j] = *((const uint2v*)(xn + (ptrdiff_t)pix * C_) + li);
        }
#pragma unroll
        for (int j = 0; j < 18; ++j) {
            int r  = rb + 2 * j;
            int k  = r >> 3;
            int p0 = (r & 7) * 2;
            int kh = k / 3, kw = k - kh * 3;
            int y  = ho - 1 + kh;
            int xx = wo0 + 16 * tl + p0 - 1 + kw;
            bool vy = (unsigned)y < (unsigned)H_;
            // lanes 0..15 hold pixel p0 (tap xx), lanes 16..31 hold p0+1 (tap xx+1)
            int myxx = xx + (li >> 4);
            bool valid = vy && ((unsigned)myxx < (unsigned)W_);
            uint2v v = ua[j];
            v.x = valid ? v.x : 0u;
            v.y = valid ? v.y : 0u;
            int p = p0 + (li >> 4);
            *(uint2v*)&s_x[tl][p * SST + k * 64 + 4 * (li & 15)] = v;
        }
    }
    __syncthreads();

    // ---- Phase B: offset conv, 4 waves = (row-tile r, K-half h); B from LDS; A shared ----
    {
        int r = wv >> 1;
        int h = wv & 1;
        const __bf16* ar = w_off2 + (size_t)(16 * r + col) * CK + h * 288 + q * 8;
        const __bf16* b0 = s_x[0] + col * SST + h * 288 + q * 8;
        const __bf16* b1 = s_x[1] + col * SST + h * 288 + q * 8;
        floatx4 acc0 = {0.f, 0.f, 0.f, 0.f}, acc1 = {0.f, 0.f, 0.f, 0.f};
#pragma unroll
        for (int it = 0; it < 9; ++it) {
            bf16x8 a   = *(const bf16x8*)(ar + 32 * it);
            bf16x8 bb0 = *(const bf16x8*)(b0 + 32 * it);
            bf16x8 bb1 = *(const bf16x8*)(b1 + 32 * it);
            acc0 = __builtin_amdgcn_mfma_f32_16x16x32_bf16(a, bb0, acc0, 0, 0, 0);
            acc1 = __builtin_amdgcn_mfma_f32_16x16x32_bf16(a, bb1, acc1, 0, 0, 0);
        }
#pragma unroll
        for (int rr = 0; rr < 4; ++rr) {
            s_om[0][h][(16 * r + q * 4 + rr) * TP + col] = acc0[rr];
            s_om[1][h][(16 * r + q * 4 + rr) * TP + col] = acc1[rr];
        }
    }
    __syncthreads();

    // ---- coords: position-weights + clamped base pixel (288 items, 2 passes) ----
#pragma unroll
    for (int it2 = 0; it2 < 2; ++it2) {
        int i = it2 * 256 + t;
        if (i < NT * K2_ * TP) {
            int tl = (i >= 144);
            int P  = i - 144 * tl;
            int k  = P >> 4;
            int pp = P & 15;
            float dy = s_om[tl][0][(2 * k) * TP + pp]     + s_om[tl][1][(2 * k) * TP + pp]     + b_off[2 * k];
            float dx = s_om[tl][0][(2 * k + 1) * TP + pp] + s_om[tl][1][(2 * k + 1) * TP + pp] + b_off[2 * k + 1];
            float mm = s_om[tl][0][(18 + k) * TP + pp]    + s_om[tl][1][(18 + k) * TP + pp]    + b_off[18 + k];
            float msk = 1.f / (1.f + expf(-mm));
            int kh = k / 3, kw = k - kh * 3;
            float py = (float)(ho - 1 + kh) + dy;
            float px = (float)(wo0 + 16 * tl + pp - 1 + kw) + dx;
            float yf = floorf(py), xf = floorf(px);
            float fy = py - yf, fx = px - xf;
            int y0 = (int)yf, x0 = (int)xf;
            float wy0 = ((unsigned)y0 < (unsigned)H_)       ? 1.f - fy : 0.f;
            float wy1 = ((unsigned)(y0 + 1) < (unsigned)H_) ? fy       : 0.f;
            float wx0 = ((unsigned)x0 < (unsigned)W_)       ? 1.f - fx : 0.f;
            float wx1 = ((unsigned)(x0 + 1) < (unsigned)W_) ? fx      : 0.f;
            int y0c = min(max(y0, 0), H_ - 2);
            int x0c = min(max(x0, 0), W_ - 2);
            // shift weights onto clamped positions (OOB-safe addresses, exact zeros)
            float t0 = (y0 == y0c) ? wy0 : ((y0 + 1 == y0c) ? wy1 : 0.f);
            float t1 = (y0 == y0c) ? wy1 : ((y0 == y0c + 1) ? wy0 : 0.f);
            float u0 = (x0 == x0c) ? wx0 : ((x0 + 1 == x0c) ? wx1 : 0.f);
            float u1 = (x0 == x0c) ? wx1 : ((x0 == x0c + 1) ? wx0 : 0.f);
            floatx4 w4 = { t0 * u0 * msk, t0 * u1 * msk, t1 * u0 * msk, t1 * u1 * msk };
            s_w4[tl][P] = w4;
            s_pix[tl][P] = y0c * W_ + x0c;
        }
    }
    __syncthreads();

    // ---- Phase C: bilinear sample; half-wave per (k,p); 36 groups, depth-3 pipeline ----
    {
        int Pb = wv * 36 + half;
        unsigned buf[4][4];
#pragma unroll
        for (int g = 0; g < 3; ++g) {               // prologue (all in tile 0)
            int pix = s_pix[0][Pb + 2 * g];
            const unsigned* bp = (const unsigned*)(xn + (size_t)pix * C_) + li;
            buf[g][0] = bp[0];
            buf[g][1] = bp[32];
            buf[g][2] = bp[W_ * 32];
            buf[g][3] = bp[W_ * 32 + 32];
        }
#pragma unroll
        for (int g = 0; g < 36; ++g) {
            if (g < 33) {                           // issue group g+3
                int gn = g + 3;
                int tln = (gn >= 18);
                int pix = s_pix[tln][Pb + 2 * (gn - 18 * tln)];
                const unsigned* bp = (const unsigned*)(xn + (size_t)pix * C_) + li;
                unsigned* d = buf[gn & 3];
                d[0] = bp[0];
                d[1] = bp[32];
                d[2] = bp[W_ * 32];
                d[3] = bp[W_ * 32 + 32];
            }
            int tl = (g >= 18);
            int P = Pb + 2 * (g - 18 * tl);
            floatx4 w4 = s_w4[tl][P];
            const unsigned* a = buf[g & 3];
            float lo = w4[0] * bflo(a[0]) + w4[1] * bflo(a[1])
                     + w4[2] * bflo(a[2]) + w4[3] * bflo(a[3]);
            float hi = w4[0] * bfhi(a[0]) + w4[1] * bfhi(a[1])
                     + w4[2] * bfhi(a[2]) + w4[3] * bfhi(a[3]);
            floatx2 fv = {lo, hi};
            bf16x2 bv = __builtin_convertvector(fv, bf16x2);
            int k = P >> 4, p = P & 15;
            *(unsigned*)&s_x[tl][p * SST + k * 64 + 2 * li] = __builtin_bit_cast(unsigned, bv);
        }
    }
    __syncthreads();

    // ---- Phase D: main conv MFMA, A-fragments shared across both tiles ----
    {
        const __bf16* ar = w2 + (size_t)(16 * wv + col) * CK + q * 8;
        const __bf16* b0 = s_x[0] + col * SST + q * 8;
        const __bf16* b1 = s_x[1] + col * SST + q * 8;
        floatx4 acc0 = {0.f, 0.f, 0.f, 0.f}, acc1 = {0.f, 0.f, 0.f, 0.f};
        bf16x8 a_cur = *(const bf16x8*)ar;
#pragma unroll
        for (int it = 0; it < 18; ++it) {
            bf16x8 a_nxt;
            if (it < 17) a_nxt = *(const bf16x8*)(ar + 32 * (it + 1));
            bf16x8 bb0 = *(const bf16x8*)(b0 + 32 * it);
            bf16x8 bb1 = *(const bf16x8*)(b1 + 32 * it);
            acc0 = __builtin_amdgcn_mfma_f32_16x16x32_bf16(a_cur, bb0, acc0, 0, 0, 0);
            acc1 = __builtin_amdgcn_mfma_f32_16x16x32_bf16(a_cur, bb1, acc1, 0, 0, 0);
            a_cur = a_nxt;
        }
#pragma unroll
        for (int r = 0; r < 4; ++r) {
            int o = 16 * wv + q * 4 + r;
            float bias = b[o];
            float* ob = out + (((size_t)n * COUT + o) * H_ + ho) * W_ + wo0;
            ob[col]      = fmaxf(acc0[r] + bias, 0.f);
            ob[16 + col] = fmaxf(acc1[r] + bias, 0.f);
        }
    }
}

extern "C" void kernel_launch(void* const* d_in, const int* in_sizes, int n_in,
                              void* d_out, int out_size, void* d_ws, size_t ws_size,
                              hipStream_t stream) {
    const float* x     = (const float*)d_in[0];
    const float* w_off = (const float*)d_in[1];
    const float* b_off = (const float*)d_in[2];
    const float* w     = (const float*)d_in[3];
    const float* b     = (const float*)d_in[4];
    float* out = (float*)d_out;

    // workspace: [256B guard][xT NHWC bf16 8.39MB][256B guard][w2][w_off2]
    __bf16* xT     = (__bf16*)d_ws + GUARD;
    __bf16* w2     = xT + (size_t)N_ * HW_ * C_ + GUARD;
    __bf16* w_off2 = w2 + (size_t)COUT * CK;

    prep_kernel<<<dim3(5, 128, 4), 256, 0, stream>>>(x, w, w_off, xT, w2, w_off2);

    int nblocks = N_ * H_ * W_ / (TP * NT);   // 2048
    fused_kernel<<<nblocks, 256, 0, stream>>>(xT, w2, w_off2, b_off, b, out);
}